// Round 5
// baseline (423.346 us; speedup 1.0000x reference)
//
#include <hip/hip_runtime.h>

#define NN 100000
#define EE 1600000
#define CH 128

typedef _Float16 h2 __attribute__((ext_vector_type(2)));
typedef _Float16 h8 __attribute__((ext_vector_type(8)));
typedef float f32x4 __attribute__((ext_vector_type(4)));

// bucketed CSR build params
#define S_NODES 512
#define NBUCK 196
#define CAP_E 10240

// chunk-split feature layout: element (n, ch) lives at
//   [ (ch>>4) * (NN*16) + n*16 + (ch&15) ]
#define CHUNK_STRIDE ((size_t)NN * 16)

// ---------------- Pass A: partition edges into dst-buckets ----------------

__global__ __launch_bounds__(256) void k_passA(const int* __restrict__ src, const int* __restrict__ dst,
                                               int* __restrict__ gcur, int* __restrict__ eb) {
    __shared__ int hist[NBUCK];
    __shared__ int curL[NBUCK];
    for (int t = threadIdx.x; t < NBUCK; t += 256) hist[t] = 0;
    __syncthreads();
    int base = blockIdx.x * 4096;
    int pk[16], bk[16];
#pragma unroll
    for (int j = 0; j < 16; ++j) {
        int i = base + threadIdx.x + 256 * j;
        if (i < EE) {
            int s = src[i], d = dst[i];
            bk[j] = d >> 9;
            pk[j] = (s << 9) | (d & 511);
            atomicAdd(&hist[bk[j]], 1);
        } else bk[j] = -1;
    }
    __syncthreads();
    for (int t = threadIdx.x; t < NBUCK; t += 256) {
        int h = hist[t];
        curL[t] = (h > 0) ? atomicAdd(&gcur[t], h) : 0;
    }
    __syncthreads();
#pragma unroll
    for (int j = 0; j < 16; ++j) {
        if (bk[j] >= 0) {
            int pos = atomicAdd(&curL[bk[j]], 1);
            if (pos < CAP_E) eb[bk[j] * CAP_E + pos] = pk[j];
        }
    }
}

// ---------------- bucket-base scan ----------------

__global__ __launch_bounds__(256) void k_bscan(const int* __restrict__ gcur, int* __restrict__ bbase,
                                               int* __restrict__ rp) {
    __shared__ int ts[256];
    int t = threadIdx.x;
    int nn = (t < NBUCK) ? min(S_NODES, NN - t * S_NODES) : 0;
    int v = (t < NBUCK) ? (min(gcur[t], CAP_E) + nn) : 0;
    ts[t] = v; __syncthreads();
    for (int off = 1; off < 256; off <<= 1) {
        int u = (t >= off) ? ts[t - off] : 0;
        __syncthreads();
        ts[t] += u;
        __syncthreads();
    }
    if (t < NBUCK) bbase[t] = ts[t] - v;
    if (t == 0) rp[NN] = EE + NN;
}

// ---------------- fused Pass B ----------------

__global__ __launch_bounds__(256) void k_passB(const int* __restrict__ gcur, const int* __restrict__ eb,
                                               const int* __restrict__ bbase, int* __restrict__ rp,
                                               float* __restrict__ dinv, int* __restrict__ col) {
    __shared__ int c[S_NODES];
    __shared__ int excl[S_NODES];
    __shared__ int cur[S_NODES];
    __shared__ int ts[256];
    __shared__ int stage[CAP_E + S_NODES];
    int bId = blockIdx.x;
    int nbase = bId * S_NODES;
    int tid = threadIdx.x;
    c[tid] = 0; c[tid + 256] = 0;
    __syncthreads();
    int n = min(gcur[bId], CAP_E);
    const int* e = eb + (size_t)bId * CAP_E;
    for (int i = tid; i < n; i += 256) atomicAdd(&c[e[i] & 511], 1);
    __syncthreads();
    int n0 = nbase + 2 * tid, n1 = n0 + 1;
    int v0 = (n0 < NN) ? c[2 * tid] + 1 : 0;
    int v1 = (n1 < NN) ? c[2 * tid + 1] + 1 : 0;
    int s = v0 + v1;
    ts[tid] = s; __syncthreads();
    for (int off = 1; off < 256; off <<= 1) {
        int u = (tid >= off) ? ts[tid - off] : 0;
        __syncthreads();
        ts[tid] += u;
        __syncthreads();
    }
    int ex = ts[tid] - s;
    int base = bbase[bId];
    excl[2 * tid] = ex; excl[2 * tid + 1] = ex + v0;
    cur[2 * tid] = ex;  cur[2 * tid + 1] = ex + v0;
    if (n0 < NN) { rp[n0] = base + ex;      dinv[n0] = rsqrtf((float)v0); }
    if (n1 < NN) { rp[n1] = base + ex + v0; dinv[n1] = rsqrtf((float)v1); }
    __syncthreads();
    for (int i = tid; i < n; i += 256) {
        int pe = e[i];
        int pos = atomicAdd(&cur[pe & 511], 1);
        stage[pos] = pe >> 9;
    }
    {
        int t0 = 2 * tid, t1 = 2 * tid + 1;
        if (n0 < NN) stage[excl[t0] + c[t0]] = n0;
        if (n1 < NN) stage[excl[t1] + c[t1]] = n1;
    }
    __syncthreads();
    int total = ts[255];
    for (int i = tid; i < total; i += 256) col[base + i] = stage[i];
}

// ---------------- prep: W1,W2 -> fp16 transposed; BN folds ----------------

__global__ __launch_bounds__(128) void k_prep(const float* __restrict__ W1, const float* __restrict__ W2,
                                              _Float16* __restrict__ Wt1, _Float16* __restrict__ Wt2,
                                              const float* __restrict__ b1, const float* __restrict__ g1,
                                              const float* __restrict__ be1, const float* __restrict__ rm1,
                                              const float* __restrict__ rv1,
                                              const float* __restrict__ b2, const float* __restrict__ g2,
                                              const float* __restrict__ be2, const float* __restrict__ rm2,
                                              const float* __restrict__ rv2,
                                              float* __restrict__ sc1, float* __restrict__ sh1,
                                              float* __restrict__ sc2, float* __restrict__ sh2) {
    int bid = blockIdx.x, t = threadIdx.x;
    if (bid < 128) {
        Wt1[bid * 128 + t] = (_Float16)W1[t * 128 + bid];
    } else if (bid < 256) {
        int nn = bid - 128;
        Wt2[nn * 128 + t] = (_Float16)W2[t * 128 + nn];
    } else if (bid == 256) {
        float sv = g1[t] * rsqrtf(rv1[t] + 1e-5f);
        sc1[t] = sv;
        sh1[t] = (b1[t] - rm1[t]) * sv + be1[t];
    } else {
        float sv = g2[t] * rsqrtf(rv2[t] + 1e-5f);
        sc2[t] = sv;
        sh2[t] = (b2[t] - rm2[t]) * sv + be2[t];
    }
}

// ---------------- MFMA GEMM [N,128]@[128,128] ----------------
// F32IN: A fp32 row-major (input x). Else A fp16 chunk-split.
// C written fp16 chunk-split, epilogue row *= dinv.

template <bool F32IN>
__global__ __launch_bounds__(256) void k_gemm_mfma(const void* __restrict__ Ain,
                                                   const _Float16* __restrict__ Wt,
                                                   const float* __restrict__ dinv,
                                                   _Float16* __restrict__ C) {
    __shared__ _Float16 Wl[CH * CH];  // 32 KB, [row][16B-slot XOR-swizzled]
    {
        const float4* wg = (const float4*)Wt;
#pragma unroll
        for (int i = 0; i < 8; ++i) {
            int chunk = i * 256 + threadIdx.x;
            int row = chunk >> 4, slot = chunk & 15;
            float4 v = wg[chunk];
            *(float4*)((char*)Wl + row * 256 + ((slot ^ (row & 15)) * 16)) = v;
        }
    }
    __syncthreads();
    int lane = threadIdx.x & 63;
    int l15 = lane & 15, lhi = lane >> 4;
    int row0 = blockIdx.x * 64 + (threadIdx.x >> 6) * 16;
    if (row0 >= NN) return;

    h8 afrag[4];
    if (F32IN) {
        const float* Arow = (const float*)Ain + (size_t)(row0 + l15) * CH + lhi * 8;
#pragma unroll
        for (int ks = 0; ks < 4; ++ks) {
            float4 a = *(const float4*)(Arow + ks * 32);
            float4 b = *(const float4*)(Arow + ks * 32 + 4);
            h8 o;
            o[0] = (_Float16)a.x; o[1] = (_Float16)a.y; o[2] = (_Float16)a.z; o[3] = (_Float16)a.w;
            o[4] = (_Float16)b.x; o[5] = (_Float16)b.y; o[6] = (_Float16)b.z; o[7] = (_Float16)b.w;
            afrag[ks] = o;
        }
    } else {
        const _Float16* Ah = (const _Float16*)Ain;
        // ch = ks*32 + lhi*8 + j -> chunk = ks*2 + (lhi>>1), offset = (lhi&1)*8
#pragma unroll
        for (int ks = 0; ks < 4; ++ks) {
            int chunk = ks * 2 + (lhi >> 1);
            afrag[ks] = *(const h8*)(Ah + (size_t)chunk * CHUNK_STRIDE
                                     + (size_t)(row0 + l15) * 16 + (lhi & 1) * 8);
        }
    }

    f32x4 acc[8] = {};
#pragma unroll
    for (int ks = 0; ks < 4; ++ks) {
        int slot = ks * 4 + lhi;
#pragma unroll
        for (int c = 0; c < 8; ++c) {
            int brow = c * 16 + l15;
            h8 b = *(const h8*)((char*)Wl + brow * 256 + ((slot ^ (brow & 15)) * 16));
            acc[c] = __builtin_amdgcn_mfma_f32_16x16x32_f16(afrag[ks], b, acc[c], 0, 0, 0);
        }
    }
    float dv[4];
#pragma unroll
    for (int j = 0; j < 4; ++j) dv[j] = dinv[row0 + lhi * 4 + j];
    // D: lane holds D[lhi*4+j][c*16+l15] -> chunk-split write: chunk=c, off=l15
#pragma unroll
    for (int c = 0; c < 8; ++c)
#pragma unroll
        for (int j = 0; j < 4; ++j) {
            float v = acc[c][j] * dv[j];
            C[(size_t)c * CHUNK_STRIDE + (size_t)(row0 + lhi * 4 + j) * 16 + l15] = (_Float16)v;
        }
}

// ---------------- XCD-sliced aggregation ----------------
// Slice s = blockIdx.x & 7 (round-robins to a fixed XCD) owns channel chunk s.
// Per-XCD gather working set = 3.2 MB -> L2-resident.
// Wave: one node; lane = (edge-group 0..7) x (ch-pair 0..7); 32-edge prefetch.

#define NPW 16   // nodes per wave

__global__ __launch_bounds__(256) void k_aggs(const _Float16* __restrict__ h, const int* __restrict__ rp,
                                              const int* __restrict__ col, const float* __restrict__ dinv,
                                              const float* __restrict__ sc, const float* __restrict__ sh,
                                              _Float16* __restrict__ out) {
    int s = blockIdx.x & 7;
    int g = blockIdx.x >> 3;
    int lane = threadIdx.x & 63;
    int grp = lane >> 3, ch8 = lane & 7;
    const _Float16* hs = h + (size_t)s * CHUNK_STRIDE;
    _Float16* os = out + (size_t)s * CHUNK_STRIDE;
    float2 scv = *(const float2*)(sc + s * 16 + ch8 * 2);
    float2 shv = *(const float2*)(sh + s * 16 + ch8 * 2);
    int node0 = (g * 4 + (threadIdx.x >> 6)) * NPW;
    for (int ni = 0; ni < NPW; ++ni) {
        int node = node0 + ni;
        if (node >= NN) return;
        int beg = rp[node], end = rp[node + 1];
        int lastc = end - 1;
        int i0 = beg + grp;
        int i1 = i0 + 8, i2 = i0 + 16, i3 = i0 + 24;
        int s0 = col[i0 < end ? i0 : lastc];
        int s1 = col[i1 < end ? i1 : lastc];
        int s2 = col[i2 < end ? i2 : lastc];
        int s3 = col[i3 < end ? i3 : lastc];
        h2 v0 = *(const h2*)(hs + (size_t)s0 * 16 + ch8 * 2);
        h2 v1 = *(const h2*)(hs + (size_t)s1 * 16 + ch8 * 2);
        h2 v2 = *(const h2*)(hs + (size_t)s2 * 16 + ch8 * 2);
        h2 v3 = *(const h2*)(hs + (size_t)s3 * 16 + ch8 * 2);
        float ax = (i0 < end ? (float)v0[0] : 0.f) + (i1 < end ? (float)v1[0] : 0.f)
                 + (i2 < end ? (float)v2[0] : 0.f) + (i3 < end ? (float)v3[0] : 0.f);
        float ay = (i0 < end ? (float)v0[1] : 0.f) + (i1 < end ? (float)v1[1] : 0.f)
                 + (i2 < end ? (float)v2[1] : 0.f) + (i3 < end ? (float)v3[1] : 0.f);
        for (int e = beg + 32; e < end; e += 8) {   // rare: degree > 32
            int idx = e + grp;
            int sr = col[idx < end ? idx : lastc];
            h2 v = *(const h2*)(hs + (size_t)sr * 16 + ch8 * 2);
            if (idx < end) { ax += (float)v[0]; ay += (float)v[1]; }
        }
        ax += __shfl_xor(ax, 8);  ay += __shfl_xor(ay, 8);
        ax += __shfl_xor(ax, 16); ay += __shfl_xor(ay, 16);
        ax += __shfl_xor(ax, 32); ay += __shfl_xor(ay, 32);
        if (grp == 0) {
            float dvn = dinv[node];
            float o0 = fmaxf(fmaf(ax * dvn, scv.x, shv.x), 0.f);
            float o1 = fmaxf(fmaf(ay * dvn, scv.y, shv.y), 0.f);
            h2 o; o[0] = (_Float16)o0; o[1] = (_Float16)o1;
            *(h2*)(os + (size_t)node * 16 + ch8 * 2) = o;
        }
    }
}

// ---------------- Layer 3 ----------------

__global__ __launch_bounds__(256) void k_gemm_out(const _Float16* __restrict__ A, const float* __restrict__ W3,
                                                  const float* __restrict__ dinv, float* __restrict__ H3) {
    __shared__ float w3s[256];
    w3s[threadIdx.x] = W3[threadIdx.x];
    __syncthreads();
    int n = blockIdx.x * 256 + threadIdx.x;
    if (n >= NN) return;
    float a0 = 0.f, a1 = 0.f;
#pragma unroll
    for (int c = 0; c < 8; ++c) {
        h8 a = *(const h8*)(A + (size_t)c * CHUNK_STRIDE + (size_t)n * 16);
        h8 b = *(const h8*)(A + (size_t)c * CHUNK_STRIDE + (size_t)n * 16 + 8);
#pragma unroll
        for (int j = 0; j < 8; ++j) {
            int k = c * 16 + j;
            a0 += (float)a[j] * w3s[k * 2];
            a1 += (float)a[j] * w3s[k * 2 + 1];
        }
#pragma unroll
        for (int j = 0; j < 8; ++j) {
            int k = c * 16 + 8 + j;
            a0 += (float)b[j] * w3s[k * 2];
            a1 += (float)b[j] * w3s[k * 2 + 1];
        }
    }
    float dv = dinv[n];
    *(float2*)(H3 + (size_t)n * 2) = make_float2(a0 * dv, a1 * dv);
}

__global__ __launch_bounds__(256) void k_agg_out(const float* __restrict__ H3, const int* __restrict__ rp,
                                                 const int* __restrict__ col, const float* __restrict__ dinv,
                                                 const float* __restrict__ b3, float* __restrict__ out) {
    int n = blockIdx.x * 256 + threadIdx.x;
    if (n >= NN) return;
    int beg = rp[n], end = rp[n + 1];
    float a0 = 0.f, a1 = 0.f;
    for (int e = beg; e < end; ++e) {
        int s = col[e];
        float2 hv = *(const float2*)(H3 + (size_t)s * 2);
        a0 += hv.x;
        a1 += hv.y;
    }
    float dv = dinv[n];
    out[(size_t)n * 2 + 0] = fmaf(a0, dv, b3[0]);
    out[(size_t)n * 2 + 1] = fmaf(a1, dv, b3[1]);
}

// ---------------- launch ----------------

extern "C" void kernel_launch(void* const* d_in, const int* in_sizes, int n_in,
                              void* d_out, int out_size, void* d_ws, size_t ws_size,
                              hipStream_t stream) {
    const float* x  = (const float*)d_in[0];
    const int* ei   = (const int*)d_in[1];
    const int* src  = ei;
    const int* dst  = ei + EE;
    const float* W1 = (const float*)d_in[2];
    const float* b1 = (const float*)d_in[3];
    const float* g1 = (const float*)d_in[4];
    const float* be1 = (const float*)d_in[5];
    const float* rm1 = (const float*)d_in[6];
    const float* rv1 = (const float*)d_in[7];
    const float* W2 = (const float*)d_in[8];
    const float* b2 = (const float*)d_in[9];
    const float* g2 = (const float*)d_in[10];
    const float* be2 = (const float*)d_in[11];
    const float* rm2 = (const float*)d_in[12];
    const float* rv2 = (const float*)d_in[13];
    const float* W3 = (const float*)d_in[14];
    const float* b3 = (const float*)d_in[15];
    float* out = (float*)d_out;

    char* p = (char*)d_ws;
    auto carve = [&](size_t bytes) -> void* {
        void* r = (void*)p;
        p += (bytes + 255) & ~(size_t)255;
        return r;
    };
    int* rp     = (int*)carve((size_t)(NN + 1) * 4);
    float* dinv = (float*)carve((size_t)NN * 4);
    int* col    = (int*)carve((size_t)(EE + NN) * 4);
    int* bbase  = (int*)carve(256 * 4);
    float* sc1  = (float*)carve(128 * 4);
    float* sh1  = (float*)carve(128 * 4);
    float* sc2  = (float*)carve(128 * 4);
    float* sh2  = (float*)carve(128 * 4);
    _Float16* bufA = (_Float16*)carve((size_t)NN * CH * 2);
    _Float16* bufB = (_Float16*)carve((size_t)NN * CH * 2);
    _Float16* Wt1  = (_Float16*)carve(128 * 128 * 2);
    _Float16* Wt2  = (_Float16*)carve(128 * 128 * 2);
    float* h3   = (float*)carve((size_t)NN * 2 * 4);

    // bucket workspace aliases bufA (dead until first GEMM)
    int* eb   = (int*)bufA;
    int* gcur = eb + (size_t)NBUCK * CAP_E;

    hipMemsetAsync(gcur, 0, (size_t)NBUCK * 4, stream);

    k_passA<<<(EE + 4095) / 4096, 256, 0, stream>>>(src, dst, gcur, eb);
    k_bscan<<<1, 256, 0, stream>>>(gcur, bbase, rp);
    k_passB<<<NBUCK, 256, 0, stream>>>(gcur, eb, bbase, rp, dinv, col);
    k_prep<<<258, 128, 0, stream>>>(W1, W2, Wt1, Wt2,
                                    b1, g1, be1, rm1, rv1,
                                    b2, g2, be2, rm2, rv2,
                                    sc1, sh1, sc2, sh2);

    int aggBlocks = 8 * ((NN + 4 * NPW - 1) / (4 * NPW));
    k_gemm_mfma<true><<<(NN + 63) / 64, 256, 0, stream>>>(x, Wt1, dinv, bufA);
    k_aggs<<<aggBlocks, 256, 0, stream>>>(bufA, rp, col, dinv, sc1, sh1, bufB);
    k_gemm_mfma<false><<<(NN + 63) / 64, 256, 0, stream>>>(bufB, Wt2, dinv, bufA);
    k_aggs<<<aggBlocks, 256, 0, stream>>>(bufA, rp, col, dinv, sc2, sh2, bufB);
    k_gemm_out<<<(NN + 255) / 256, 256, 0, stream>>>(bufB, W3, dinv, h3);
    k_agg_out<<<(NN + 255) / 256, 256, 0, stream>>>(h3, rp, col, dinv, b3, out);
}

// Round 6
// 333.024 us; speedup vs baseline: 1.2712x; 1.2712x over previous
//
#include <hip/hip_runtime.h>

#define NN 100000
#define EE 1600000
#define CH 128

typedef _Float16 h2 __attribute__((ext_vector_type(2)));
typedef _Float16 h8 __attribute__((ext_vector_type(8)));
typedef float f32x4 __attribute__((ext_vector_type(4)));

// bucketed CSR build params
#define S_NODES 512
#define NBUCK 196
#define CAP_E 10240

// chunk-split feature layout: element (n, ch) lives at
//   [ (ch>>4) * (NN*16) + n*16 + (ch&15) ]
#define CHUNK_STRIDE ((size_t)NN * 16)

// ---------------- Pass A: partition edges into dst-buckets ----------------

__global__ __launch_bounds__(256) void k_passA(const int* __restrict__ src, const int* __restrict__ dst,
                                               int* __restrict__ gcur, int* __restrict__ eb) {
    __shared__ int hist[NBUCK];
    __shared__ int curL[NBUCK];
    for (int t = threadIdx.x; t < NBUCK; t += 256) hist[t] = 0;
    __syncthreads();
    int base = blockIdx.x * 4096;
    int pk[16], bk[16];
#pragma unroll
    for (int j = 0; j < 16; ++j) {
        int i = base + threadIdx.x + 256 * j;
        if (i < EE) {
            int s = src[i], d = dst[i];
            bk[j] = d >> 9;
            pk[j] = (s << 9) | (d & 511);
            atomicAdd(&hist[bk[j]], 1);
        } else bk[j] = -1;
    }
    __syncthreads();
    for (int t = threadIdx.x; t < NBUCK; t += 256) {
        int h = hist[t];
        curL[t] = (h > 0) ? atomicAdd(&gcur[t], h) : 0;
    }
    __syncthreads();
#pragma unroll
    for (int j = 0; j < 16; ++j) {
        if (bk[j] >= 0) {
            int pos = atomicAdd(&curL[bk[j]], 1);
            if (pos < CAP_E) eb[bk[j] * CAP_E + pos] = pk[j];
        }
    }
}

// ---------------- bucket-base scan ----------------

__global__ __launch_bounds__(256) void k_bscan(const int* __restrict__ gcur, int* __restrict__ bbase,
                                               int* __restrict__ rp) {
    __shared__ int ts[256];
    int t = threadIdx.x;
    int nn = (t < NBUCK) ? min(S_NODES, NN - t * S_NODES) : 0;
    int v = (t < NBUCK) ? (min(gcur[t], CAP_E) + nn) : 0;
    ts[t] = v; __syncthreads();
    for (int off = 1; off < 256; off <<= 1) {
        int u = (t >= off) ? ts[t - off] : 0;
        __syncthreads();
        ts[t] += u;
        __syncthreads();
    }
    if (t < NBUCK) bbase[t] = ts[t] - v;
    if (t == 0) rp[NN] = EE + NN;
}

// ---------------- fused Pass B ----------------

__global__ __launch_bounds__(256) void k_passB(const int* __restrict__ gcur, const int* __restrict__ eb,
                                               const int* __restrict__ bbase, int* __restrict__ rp,
                                               float* __restrict__ dinv, int* __restrict__ col) {
    __shared__ int c[S_NODES];
    __shared__ int excl[S_NODES];
    __shared__ int cur[S_NODES];
    __shared__ int ts[256];
    __shared__ int stage[CAP_E + S_NODES];
    int bId = blockIdx.x;
    int nbase = bId * S_NODES;
    int tid = threadIdx.x;
    c[tid] = 0; c[tid + 256] = 0;
    __syncthreads();
    int n = min(gcur[bId], CAP_E);
    const int* e = eb + (size_t)bId * CAP_E;
    for (int i = tid; i < n; i += 256) atomicAdd(&c[e[i] & 511], 1);
    __syncthreads();
    int n0 = nbase + 2 * tid, n1 = n0 + 1;
    int v0 = (n0 < NN) ? c[2 * tid] + 1 : 0;
    int v1 = (n1 < NN) ? c[2 * tid + 1] + 1 : 0;
    int s = v0 + v1;
    ts[tid] = s; __syncthreads();
    for (int off = 1; off < 256; off <<= 1) {
        int u = (tid >= off) ? ts[tid - off] : 0;
        __syncthreads();
        ts[tid] += u;
        __syncthreads();
    }
    int ex = ts[tid] - s;
    int base = bbase[bId];
    excl[2 * tid] = ex; excl[2 * tid + 1] = ex + v0;
    cur[2 * tid] = ex;  cur[2 * tid + 1] = ex + v0;
    if (n0 < NN) { rp[n0] = base + ex;      dinv[n0] = rsqrtf((float)v0); }
    if (n1 < NN) { rp[n1] = base + ex + v0; dinv[n1] = rsqrtf((float)v1); }
    __syncthreads();
    for (int i = tid; i < n; i += 256) {
        int pe = e[i];
        int pos = atomicAdd(&cur[pe & 511], 1);
        stage[pos] = pe >> 9;
    }
    {
        int t0 = 2 * tid, t1 = 2 * tid + 1;
        if (n0 < NN) stage[excl[t0] + c[t0]] = n0;
        if (n1 < NN) stage[excl[t1] + c[t1]] = n1;
    }
    __syncthreads();
    int total = ts[255];
    for (int i = tid; i < total; i += 256) col[base + i] = stage[i];
}

// ---------------- prep: W1,W2 -> fp16 transposed; BN folds ----------------

__global__ __launch_bounds__(128) void k_prep(const float* __restrict__ W1, const float* __restrict__ W2,
                                              _Float16* __restrict__ Wt1, _Float16* __restrict__ Wt2,
                                              const float* __restrict__ b1, const float* __restrict__ g1,
                                              const float* __restrict__ be1, const float* __restrict__ rm1,
                                              const float* __restrict__ rv1,
                                              const float* __restrict__ b2, const float* __restrict__ g2,
                                              const float* __restrict__ be2, const float* __restrict__ rm2,
                                              const float* __restrict__ rv2,
                                              float* __restrict__ sc1, float* __restrict__ sh1,
                                              float* __restrict__ sc2, float* __restrict__ sh2) {
    int bid = blockIdx.x, t = threadIdx.x;
    if (bid < 128) {
        Wt1[bid * 128 + t] = (_Float16)W1[t * 128 + bid];
    } else if (bid < 256) {
        int nn = bid - 128;
        Wt2[nn * 128 + t] = (_Float16)W2[t * 128 + nn];
    } else if (bid == 256) {
        float sv = g1[t] * rsqrtf(rv1[t] + 1e-5f);
        sc1[t] = sv;
        sh1[t] = (b1[t] - rm1[t]) * sv + be1[t];
    } else {
        float sv = g2[t] * rsqrtf(rv2[t] + 1e-5f);
        sc2[t] = sv;
        sh2[t] = (b2[t] - rm2[t]) * sv + be2[t];
    }
}

// ---------------- MFMA GEMM [N,128]@[128,128] ----------------
// F32IN: A fp32 row-major (input x). Else A fp16 chunk-split.
// C written fp16 chunk-split, epilogue row *= dinv.

template <bool F32IN>
__global__ __launch_bounds__(256) void k_gemm_mfma(const void* __restrict__ Ain,
                                                   const _Float16* __restrict__ Wt,
                                                   const float* __restrict__ dinv,
                                                   _Float16* __restrict__ C) {
    __shared__ _Float16 Wl[CH * CH];  // 32 KB, [row][16B-slot XOR-swizzled]
    {
        const float4* wg = (const float4*)Wt;
#pragma unroll
        for (int i = 0; i < 8; ++i) {
            int chunk = i * 256 + threadIdx.x;
            int row = chunk >> 4, slot = chunk & 15;
            float4 v = wg[chunk];
            *(float4*)((char*)Wl + row * 256 + ((slot ^ (row & 15)) * 16)) = v;
        }
    }
    __syncthreads();
    int lane = threadIdx.x & 63;
    int l15 = lane & 15, lhi = lane >> 4;
    int row0 = blockIdx.x * 64 + (threadIdx.x >> 6) * 16;
    if (row0 >= NN) return;

    h8 afrag[4];
    if (F32IN) {
        const float* Arow = (const float*)Ain + (size_t)(row0 + l15) * CH + lhi * 8;
#pragma unroll
        for (int ks = 0; ks < 4; ++ks) {
            float4 a = *(const float4*)(Arow + ks * 32);
            float4 b = *(const float4*)(Arow + ks * 32 + 4);
            h8 o;
            o[0] = (_Float16)a.x; o[1] = (_Float16)a.y; o[2] = (_Float16)a.z; o[3] = (_Float16)a.w;
            o[4] = (_Float16)b.x; o[5] = (_Float16)b.y; o[6] = (_Float16)b.z; o[7] = (_Float16)b.w;
            afrag[ks] = o;
        }
    } else {
        const _Float16* Ah = (const _Float16*)Ain;
        // ch = ks*32 + lhi*8 + j -> chunk = ks*2 + (lhi>>1), offset = (lhi&1)*8
#pragma unroll
        for (int ks = 0; ks < 4; ++ks) {
            int chunk = ks * 2 + (lhi >> 1);
            afrag[ks] = *(const h8*)(Ah + (size_t)chunk * CHUNK_STRIDE
                                     + (size_t)(row0 + l15) * 16 + (lhi & 1) * 8);
        }
    }

    f32x4 acc[8] = {};
#pragma unroll
    for (int ks = 0; ks < 4; ++ks) {
        int slot = ks * 4 + lhi;
#pragma unroll
        for (int c = 0; c < 8; ++c) {
            int brow = c * 16 + l15;
            h8 b = *(const h8*)((char*)Wl + brow * 256 + ((slot ^ (brow & 15)) * 16));
            acc[c] = __builtin_amdgcn_mfma_f32_16x16x32_f16(afrag[ks], b, acc[c], 0, 0, 0);
        }
    }
    float dv[4];
#pragma unroll
    for (int j = 0; j < 4; ++j) dv[j] = dinv[row0 + lhi * 4 + j];
    // D: lane holds D[lhi*4+j][c*16+l15] -> chunk-split write: chunk=c, off=l15
#pragma unroll
    for (int c = 0; c < 8; ++c)
#pragma unroll
        for (int j = 0; j < 4; ++j) {
            float v = acc[c][j] * dv[j];
            C[(size_t)c * CHUNK_STRIDE + (size_t)(row0 + lhi * 4 + j) * 16 + l15] = (_Float16)v;
        }
}

// ---------------- XCD-sliced aggregation v2 ----------------
// Slice s = blockIdx.x & 7 -> fixed XCD; per-XCD gather table = 3.2 MB (L2-resident).
// Wave = 8 nodes in parallel: lane = (node-group g 0..7) x (ch-pair c 0..7).
// Lane owns its ch-pair for the whole edge loop -> no cross-lane reduction.
// Single shfl-max for wave-uniform-ish loop bound; predication = 0/1 mask in fmaf.

__global__ __launch_bounds__(256) void k_aggs3(const _Float16* __restrict__ h, const int* __restrict__ rp,
                                               const int* __restrict__ col, const float* __restrict__ dinv,
                                               const float* __restrict__ sc, const float* __restrict__ sh,
                                               _Float16* __restrict__ out) {
    int s = blockIdx.x & 7;
    int gb = blockIdx.x >> 3;
    int lane = threadIdx.x & 63;
    int g = lane >> 3;          // node sub-index 0..7
    int c = lane & 7;           // ch-pair 0..7
    int node = gb * 32 + (threadIdx.x >> 6) * 8 + g;   // NN % 32 == 0: always < NN
    int beg = rp[node];
    int end = rp[node + 1];
    int deg = end - beg;
    int md = deg;
    md = max(md, __shfl_xor(md, 8));
    md = max(md, __shfl_xor(md, 16));
    md = max(md, __shfl_xor(md, 32));
    const _Float16* hs = h + (size_t)s * CHUNK_STRIDE;
    float ax = 0.f, ay = 0.f;
    for (int e = 0; e < md; e += 2) {
        int i0 = beg + e, i1 = i0 + 1;
        int s0 = col[i0 < end ? i0 : beg];
        int s1 = col[i1 < end ? i1 : beg];
        float m0 = (i0 < end) ? 1.f : 0.f;
        float m1 = (i1 < end) ? 1.f : 0.f;
        h2 v0 = *(const h2*)(hs + ((size_t)s0 << 4) + c * 2);
        h2 v1 = *(const h2*)(hs + ((size_t)s1 << 4) + c * 2);
        ax = fmaf((float)v0[0], m0, ax);
        ay = fmaf((float)v0[1], m0, ay);
        ax = fmaf((float)v1[0], m1, ax);
        ay = fmaf((float)v1[1], m1, ay);
    }
    float dvn = dinv[node];
    float2 scv = *(const float2*)(sc + s * 16 + c * 2);
    float2 shv = *(const float2*)(sh + s * 16 + c * 2);
    float o0 = fmaxf(fmaf(ax * dvn, scv.x, shv.x), 0.f);
    float o1 = fmaxf(fmaf(ay * dvn, scv.y, shv.y), 0.f);
    h2 o; o[0] = (_Float16)o0; o[1] = (_Float16)o1;
    *(h2*)(out + (size_t)s * CHUNK_STRIDE + (size_t)node * 16 + c * 2) = o;
}

// ---------------- Layer 3 ----------------

__global__ __launch_bounds__(256) void k_gemm_out(const _Float16* __restrict__ A, const float* __restrict__ W3,
                                                  const float* __restrict__ dinv, float* __restrict__ H3) {
    __shared__ float w3s[256];
    w3s[threadIdx.x] = W3[threadIdx.x];
    __syncthreads();
    int n = blockIdx.x * 256 + threadIdx.x;
    if (n >= NN) return;
    float a0 = 0.f, a1 = 0.f;
#pragma unroll
    for (int c = 0; c < 8; ++c) {
        h8 a = *(const h8*)(A + (size_t)c * CHUNK_STRIDE + (size_t)n * 16);
        h8 b = *(const h8*)(A + (size_t)c * CHUNK_STRIDE + (size_t)n * 16 + 8);
#pragma unroll
        for (int j = 0; j < 8; ++j) {
            int k = c * 16 + j;
            a0 += (float)a[j] * w3s[k * 2];
            a1 += (float)a[j] * w3s[k * 2 + 1];
        }
#pragma unroll
        for (int j = 0; j < 8; ++j) {
            int k = c * 16 + 8 + j;
            a0 += (float)b[j] * w3s[k * 2];
            a1 += (float)b[j] * w3s[k * 2 + 1];
        }
    }
    float dv = dinv[n];
    *(float2*)(H3 + (size_t)n * 2) = make_float2(a0 * dv, a1 * dv);
}

__global__ __launch_bounds__(256) void k_agg_out(const float* __restrict__ H3, const int* __restrict__ rp,
                                                 const int* __restrict__ col, const float* __restrict__ dinv,
                                                 const float* __restrict__ b3, float* __restrict__ out) {
    int n = blockIdx.x * 256 + threadIdx.x;
    if (n >= NN) return;
    int beg = rp[n], end = rp[n + 1];
    float a0 = 0.f, a1 = 0.f;
    for (int e = beg; e < end; ++e) {
        int s = col[e];
        float2 hv = *(const float2*)(H3 + (size_t)s * 2);
        a0 += hv.x;
        a1 += hv.y;
    }
    float dv = dinv[n];
    out[(size_t)n * 2 + 0] = fmaf(a0, dv, b3[0]);
    out[(size_t)n * 2 + 1] = fmaf(a1, dv, b3[1]);
}

// ---------------- launch ----------------

extern "C" void kernel_launch(void* const* d_in, const int* in_sizes, int n_in,
                              void* d_out, int out_size, void* d_ws, size_t ws_size,
                              hipStream_t stream) {
    const float* x  = (const float*)d_in[0];
    const int* ei   = (const int*)d_in[1];
    const int* src  = ei;
    const int* dst  = ei + EE;
    const float* W1 = (const float*)d_in[2];
    const float* b1 = (const float*)d_in[3];
    const float* g1 = (const float*)d_in[4];
    const float* be1 = (const float*)d_in[5];
    const float* rm1 = (const float*)d_in[6];
    const float* rv1 = (const float*)d_in[7];
    const float* W2 = (const float*)d_in[8];
    const float* b2 = (const float*)d_in[9];
    const float* g2 = (const float*)d_in[10];
    const float* be2 = (const float*)d_in[11];
    const float* rm2 = (const float*)d_in[12];
    const float* rv2 = (const float*)d_in[13];
    const float* W3 = (const float*)d_in[14];
    const float* b3 = (const float*)d_in[15];
    float* out = (float*)d_out;

    char* p = (char*)d_ws;
    auto carve = [&](size_t bytes) -> void* {
        void* r = (void*)p;
        p += (bytes + 255) & ~(size_t)255;
        return r;
    };
    int* rp     = (int*)carve((size_t)(NN + 1) * 4);
    float* dinv = (float*)carve((size_t)NN * 4);
    int* col    = (int*)carve((size_t)(EE + NN) * 4);
    int* bbase  = (int*)carve(256 * 4);
    float* sc1  = (float*)carve(128 * 4);
    float* sh1  = (float*)carve(128 * 4);
    float* sc2  = (float*)carve(128 * 4);
    float* sh2  = (float*)carve(128 * 4);
    _Float16* bufA = (_Float16*)carve((size_t)NN * CH * 2);
    _Float16* bufB = (_Float16*)carve((size_t)NN * CH * 2);
    _Float16* Wt1  = (_Float16*)carve(128 * 128 * 2);
    _Float16* Wt2  = (_Float16*)carve(128 * 128 * 2);
    float* h3   = (float*)carve((size_t)NN * 2 * 4);

    // bucket workspace aliases bufA (dead until first GEMM)
    int* eb   = (int*)bufA;
    int* gcur = eb + (size_t)NBUCK * CAP_E;

    hipMemsetAsync(gcur, 0, (size_t)NBUCK * 4, stream);

    k_passA<<<(EE + 4095) / 4096, 256, 0, stream>>>(src, dst, gcur, eb);
    k_bscan<<<1, 256, 0, stream>>>(gcur, bbase, rp);
    k_passB<<<NBUCK, 256, 0, stream>>>(gcur, eb, bbase, rp, dinv, col);
    k_prep<<<258, 128, 0, stream>>>(W1, W2, Wt1, Wt2,
                                    b1, g1, be1, rm1, rv1,
                                    b2, g2, be2, rm2, rv2,
                                    sc1, sh1, sc2, sh2);

    int aggBlocks = 8 * (NN / 32);   // NN % 32 == 0
    k_gemm_mfma<true><<<(NN + 63) / 64, 256, 0, stream>>>(x, Wt1, dinv, bufA);
    k_aggs3<<<aggBlocks, 256, 0, stream>>>(bufA, rp, col, dinv, sc1, sh1, bufB);
    k_gemm_mfma<false><<<(NN + 63) / 64, 256, 0, stream>>>(bufB, Wt2, dinv, bufA);
    k_aggs3<<<aggBlocks, 256, 0, stream>>>(bufA, rp, col, dinv, sc2, sh2, bufB);
    k_gemm_out<<<(NN + 255) / 256, 256, 0, stream>>>(bufB, W3, dinv, h3);
    k_agg_out<<<(NN + 255) / 256, 256, 0, stream>>>(h3, rp, col, dinv, b3, out);
}

// Round 7
// 270.017 us; speedup vs baseline: 1.5679x; 1.2333x over previous
//
#include <hip/hip_runtime.h>

#define NN 100000
#define EE 1600000
#define CH 128

typedef _Float16 h2 __attribute__((ext_vector_type(2)));
typedef _Float16 h8 __attribute__((ext_vector_type(8)));
typedef float f32x4 __attribute__((ext_vector_type(4)));

// bucketed CSR build params
#define S_NODES 512
#define NBUCK 196
#define CAP_E 10240

// chunk-split feature layout: element (n, ch) lives at
//   [ (ch>>4) * (NN*16) + n*16 + (ch&15) ]
#define CHUNK_STRIDE ((size_t)NN * 16)

// ---------------- Pass A: partition edges into dst-buckets ----------------

__global__ __launch_bounds__(256) void k_passA(const int* __restrict__ src, const int* __restrict__ dst,
                                               int* __restrict__ gcur, int* __restrict__ eb) {
    __shared__ int hist[NBUCK];
    __shared__ int curL[NBUCK];
    for (int t = threadIdx.x; t < NBUCK; t += 256) hist[t] = 0;
    __syncthreads();
    int base = blockIdx.x * 4096;
    int pk[16], bk[16];
#pragma unroll
    for (int j = 0; j < 16; ++j) {
        int i = base + threadIdx.x + 256 * j;
        if (i < EE) {
            int s = src[i], d = dst[i];
            bk[j] = d >> 9;
            pk[j] = (s << 9) | (d & 511);
            atomicAdd(&hist[bk[j]], 1);
        } else bk[j] = -1;
    }
    __syncthreads();
    for (int t = threadIdx.x; t < NBUCK; t += 256) {
        int h = hist[t];
        curL[t] = (h > 0) ? atomicAdd(&gcur[t], h) : 0;
    }
    __syncthreads();
#pragma unroll
    for (int j = 0; j < 16; ++j) {
        if (bk[j] >= 0) {
            int pos = atomicAdd(&curL[bk[j]], 1);
            if (pos < CAP_E) eb[bk[j] * CAP_E + pos] = pk[j];
        }
    }
}

// ---------------- bucket-base scan ----------------

__global__ __launch_bounds__(256) void k_bscan(const int* __restrict__ gcur, int* __restrict__ bbase,
                                               int* __restrict__ rp) {
    __shared__ int ts[256];
    int t = threadIdx.x;
    int nn = (t < NBUCK) ? min(S_NODES, NN - t * S_NODES) : 0;
    int v = (t < NBUCK) ? (min(gcur[t], CAP_E) + nn) : 0;
    ts[t] = v; __syncthreads();
    for (int off = 1; off < 256; off <<= 1) {
        int u = (t >= off) ? ts[t - off] : 0;
        __syncthreads();
        ts[t] += u;
        __syncthreads();
    }
    if (t < NBUCK) bbase[t] = ts[t] - v;
    if (t == 0) rp[NN] = EE + NN;
}

// ---------------- fused Pass B ----------------

__global__ __launch_bounds__(256) void k_passB(const int* __restrict__ gcur, const int* __restrict__ eb,
                                               const int* __restrict__ bbase, int* __restrict__ rp,
                                               float* __restrict__ dinv, int* __restrict__ col) {
    __shared__ int c[S_NODES];
    __shared__ int excl[S_NODES];
    __shared__ int cur[S_NODES];
    __shared__ int ts[256];
    __shared__ int stage[CAP_E + S_NODES];
    int bId = blockIdx.x;
    int nbase = bId * S_NODES;
    int tid = threadIdx.x;
    c[tid] = 0; c[tid + 256] = 0;
    __syncthreads();
    int n = min(gcur[bId], CAP_E);
    const int* e = eb + (size_t)bId * CAP_E;
    for (int i = tid; i < n; i += 256) atomicAdd(&c[e[i] & 511], 1);
    __syncthreads();
    int n0 = nbase + 2 * tid, n1 = n0 + 1;
    int v0 = (n0 < NN) ? c[2 * tid] + 1 : 0;
    int v1 = (n1 < NN) ? c[2 * tid + 1] + 1 : 0;
    int s = v0 + v1;
    ts[tid] = s; __syncthreads();
    for (int off = 1; off < 256; off <<= 1) {
        int u = (tid >= off) ? ts[tid - off] : 0;
        __syncthreads();
        ts[tid] += u;
        __syncthreads();
    }
    int ex = ts[tid] - s;
    int base = bbase[bId];
    excl[2 * tid] = ex; excl[2 * tid + 1] = ex + v0;
    cur[2 * tid] = ex;  cur[2 * tid + 1] = ex + v0;
    if (n0 < NN) { rp[n0] = base + ex;      dinv[n0] = rsqrtf((float)v0); }
    if (n1 < NN) { rp[n1] = base + ex + v0; dinv[n1] = rsqrtf((float)v1); }
    __syncthreads();
    for (int i = tid; i < n; i += 256) {
        int pe = e[i];
        int pos = atomicAdd(&cur[pe & 511], 1);
        stage[pos] = pe >> 9;
    }
    {
        int t0 = 2 * tid, t1 = 2 * tid + 1;
        if (n0 < NN) stage[excl[t0] + c[t0]] = n0;
        if (n1 < NN) stage[excl[t1] + c[t1]] = n1;
    }
    __syncthreads();
    int total = ts[255];
    for (int i = tid; i < total; i += 256) col[base + i] = stage[i];
}

// ---------------- prep: W1,W2 -> fp16 transposed; BN folds ----------------

__global__ __launch_bounds__(128) void k_prep(const float* __restrict__ W1, const float* __restrict__ W2,
                                              _Float16* __restrict__ Wt1, _Float16* __restrict__ Wt2,
                                              const float* __restrict__ b1, const float* __restrict__ g1,
                                              const float* __restrict__ be1, const float* __restrict__ rm1,
                                              const float* __restrict__ rv1,
                                              const float* __restrict__ b2, const float* __restrict__ g2,
                                              const float* __restrict__ be2, const float* __restrict__ rm2,
                                              const float* __restrict__ rv2,
                                              float* __restrict__ sc1, float* __restrict__ sh1,
                                              float* __restrict__ sc2, float* __restrict__ sh2) {
    int bid = blockIdx.x, t = threadIdx.x;
    if (bid < 128) {
        Wt1[bid * 128 + t] = (_Float16)W1[t * 128 + bid];
    } else if (bid < 256) {
        int nn = bid - 128;
        Wt2[nn * 128 + t] = (_Float16)W2[t * 128 + nn];
    } else if (bid == 256) {
        float sv = g1[t] * rsqrtf(rv1[t] + 1e-5f);
        sc1[t] = sv;
        sh1[t] = (b1[t] - rm1[t]) * sv + be1[t];
    } else {
        float sv = g2[t] * rsqrtf(rv2[t] + 1e-5f);
        sc2[t] = sv;
        sh2[t] = (b2[t] - rm2[t]) * sv + be2[t];
    }
}

// ---------------- MFMA GEMM [N,128]@[128,128] ----------------
// F32IN: A fp32 row-major (input x). Else A fp16 chunk-split.
// C written fp16 chunk-split, epilogue row *= dinv.

template <bool F32IN>
__global__ __launch_bounds__(256) void k_gemm_mfma(const void* __restrict__ Ain,
                                                   const _Float16* __restrict__ Wt,
                                                   const float* __restrict__ dinv,
                                                   _Float16* __restrict__ C) {
    __shared__ _Float16 Wl[CH * CH];  // 32 KB, [row][16B-slot XOR-swizzled]
    {
        const float4* wg = (const float4*)Wt;
#pragma unroll
        for (int i = 0; i < 8; ++i) {
            int chunk = i * 256 + threadIdx.x;
            int row = chunk >> 4, slot = chunk & 15;
            float4 v = wg[chunk];
            *(float4*)((char*)Wl + row * 256 + ((slot ^ (row & 15)) * 16)) = v;
        }
    }
    __syncthreads();
    int lane = threadIdx.x & 63;
    int l15 = lane & 15, lhi = lane >> 4;
    int row0 = blockIdx.x * 64 + (threadIdx.x >> 6) * 16;
    if (row0 >= NN) return;

    h8 afrag[4];
    if (F32IN) {
        const float* Arow = (const float*)Ain + (size_t)(row0 + l15) * CH + lhi * 8;
#pragma unroll
        for (int ks = 0; ks < 4; ++ks) {
            float4 a = *(const float4*)(Arow + ks * 32);
            float4 b = *(const float4*)(Arow + ks * 32 + 4);
            h8 o;
            o[0] = (_Float16)a.x; o[1] = (_Float16)a.y; o[2] = (_Float16)a.z; o[3] = (_Float16)a.w;
            o[4] = (_Float16)b.x; o[5] = (_Float16)b.y; o[6] = (_Float16)b.z; o[7] = (_Float16)b.w;
            afrag[ks] = o;
        }
    } else {
        const _Float16* Ah = (const _Float16*)Ain;
        // ch = ks*32 + lhi*8 + j -> chunk = ks*2 + (lhi>>1), offset = (lhi&1)*8
#pragma unroll
        for (int ks = 0; ks < 4; ++ks) {
            int chunk = ks * 2 + (lhi >> 1);
            afrag[ks] = *(const h8*)(Ah + (size_t)chunk * CHUNK_STRIDE
                                     + (size_t)(row0 + l15) * 16 + (lhi & 1) * 8);
        }
    }

    f32x4 acc[8] = {};
#pragma unroll
    for (int ks = 0; ks < 4; ++ks) {
        int slot = ks * 4 + lhi;
#pragma unroll
        for (int c = 0; c < 8; ++c) {
            int brow = c * 16 + l15;
            h8 b = *(const h8*)((char*)Wl + brow * 256 + ((slot ^ (brow & 15)) * 16));
            acc[c] = __builtin_amdgcn_mfma_f32_16x16x32_f16(afrag[ks], b, acc[c], 0, 0, 0);
        }
    }
    float dv[4];
#pragma unroll
    for (int j = 0; j < 4; ++j) dv[j] = dinv[row0 + lhi * 4 + j];
    // D: lane holds D[lhi*4+j][c*16+l15] -> chunk-split write: chunk=c, off=l15
#pragma unroll
    for (int c = 0; c < 8; ++c)
#pragma unroll
        for (int j = 0; j < 4; ++j) {
            float v = acc[c][j] * dv[j];
            C[(size_t)c * CHUNK_STRIDE + (size_t)(row0 + lhi * 4 + j) * 16 + l15] = (_Float16)v;
        }
}

// ---------------- XCD-sliced aggregation v3: 8-deep MLP ----------------
// Slice s = blockIdx.x & 7 -> fixed XCD; per-XCD gather table = 3.2 MB (L2-resident).
// Wave = 8 nodes: lane = (node-group g 0..7) x (ch-pair c 0..7); lane owns ch-pair
// for whole loop (no reduction). 8-edge unroll: 8 independent col->h2 chains in
// flight per wave to cover the ~250cy L2-hit latency (round-6 fix: VGPR12/2-deep
// was latency-bound at 3.3x the TA floor).

__global__ __launch_bounds__(256) void k_aggs3(const _Float16* __restrict__ h, const int* __restrict__ rp,
                                               const int* __restrict__ col, const float* __restrict__ dinv,
                                               const float* __restrict__ sc, const float* __restrict__ sh,
                                               _Float16* __restrict__ out) {
    int s = blockIdx.x & 7;
    int gb = blockIdx.x >> 3;
    int lane = threadIdx.x & 63;
    int g = lane >> 3;          // node sub-index 0..7
    int c = lane & 7;           // ch-pair 0..7
    int node = gb * 32 + (threadIdx.x >> 6) * 8 + g;   // NN % 32 == 0: always < NN
    int beg = rp[node];
    int end = rp[node + 1];
    int md = end - beg;
    md = max(md, __shfl_xor(md, 8));
    md = max(md, __shfl_xor(md, 16));
    md = max(md, __shfl_xor(md, 32));
    const _Float16* hs = h + (size_t)s * CHUNK_STRIDE;
    float ax = 0.f, ay = 0.f, bx = 0.f, by = 0.f;
    for (int e = 0; e < md; e += 8) {
        int sv[8]; float m[8];
#pragma unroll
        for (int j = 0; j < 8; ++j) {
            int i = beg + e + j;
            m[j] = (i < end) ? 1.f : 0.f;
            sv[j] = col[i < end ? i : beg];
        }
        h2 v[8];
#pragma unroll
        for (int j = 0; j < 8; ++j)
            v[j] = *(const h2*)(hs + ((size_t)sv[j] << 4) + c * 2);
#pragma unroll
        for (int j = 0; j < 8; j += 2) {
            ax = fmaf((float)v[j][0],     m[j],     ax);
            ay = fmaf((float)v[j][1],     m[j],     ay);
            bx = fmaf((float)v[j + 1][0], m[j + 1], bx);
            by = fmaf((float)v[j + 1][1], m[j + 1], by);
        }
    }
    ax += bx; ay += by;
    float dvn = dinv[node];
    float2 scv = *(const float2*)(sc + s * 16 + c * 2);
    float2 shv = *(const float2*)(sh + s * 16 + c * 2);
    float o0 = fmaxf(fmaf(ax * dvn, scv.x, shv.x), 0.f);
    float o1 = fmaxf(fmaf(ay * dvn, scv.y, shv.y), 0.f);
    h2 o; o[0] = (_Float16)o0; o[1] = (_Float16)o1;
    *(h2*)(out + (size_t)s * CHUNK_STRIDE + (size_t)node * 16 + c * 2) = o;
}

// ---------------- Layer 3 ----------------

__global__ __launch_bounds__(256) void k_gemm_out(const _Float16* __restrict__ A, const float* __restrict__ W3,
                                                  const float* __restrict__ dinv, float* __restrict__ H3) {
    __shared__ float w3s[256];
    w3s[threadIdx.x] = W3[threadIdx.x];
    __syncthreads();
    int n = blockIdx.x * 256 + threadIdx.x;
    if (n >= NN) return;
    float a0 = 0.f, a1 = 0.f;
#pragma unroll
    for (int c = 0; c < 8; ++c) {
        h8 a = *(const h8*)(A + (size_t)c * CHUNK_STRIDE + (size_t)n * 16);
        h8 b = *(const h8*)(A + (size_t)c * CHUNK_STRIDE + (size_t)n * 16 + 8);
#pragma unroll
        for (int j = 0; j < 8; ++j) {
            int k = c * 16 + j;
            a0 += (float)a[j] * w3s[k * 2];
            a1 += (float)a[j] * w3s[k * 2 + 1];
        }
#pragma unroll
        for (int j = 0; j < 8; ++j) {
            int k = c * 16 + 8 + j;
            a0 += (float)b[j] * w3s[k * 2];
            a1 += (float)b[j] * w3s[k * 2 + 1];
        }
    }
    float dv = dinv[n];
    *(float2*)(H3 + (size_t)n * 2) = make_float2(a0 * dv, a1 * dv);
}

__global__ __launch_bounds__(256) void k_agg_out(const float* __restrict__ H3, const int* __restrict__ rp,
                                                 const int* __restrict__ col, const float* __restrict__ dinv,
                                                 const float* __restrict__ b3, float* __restrict__ out) {
    int n = blockIdx.x * 256 + threadIdx.x;
    if (n >= NN) return;
    int beg = rp[n], end = rp[n + 1];
    float a0 = 0.f, a1 = 0.f;
    for (int e = beg; e < end; ++e) {
        int s = col[e];
        float2 hv = *(const float2*)(H3 + (size_t)s * 2);
        a0 += hv.x;
        a1 += hv.y;
    }
    float dv = dinv[n];
    out[(size_t)n * 2 + 0] = fmaf(a0, dv, b3[0]);
    out[(size_t)n * 2 + 1] = fmaf(a1, dv, b3[1]);
}

// ---------------- launch ----------------

extern "C" void kernel_launch(void* const* d_in, const int* in_sizes, int n_in,
                              void* d_out, int out_size, void* d_ws, size_t ws_size,
                              hipStream_t stream) {
    const float* x  = (const float*)d_in[0];
    const int* ei   = (const int*)d_in[1];
    const int* src  = ei;
    const int* dst  = ei + EE;
    const float* W1 = (const float*)d_in[2];
    const float* b1 = (const float*)d_in[3];
    const float* g1 = (const float*)d_in[4];
    const float* be1 = (const float*)d_in[5];
    const float* rm1 = (const float*)d_in[6];
    const float* rv1 = (const float*)d_in[7];
    const float* W2 = (const float*)d_in[8];
    const float* b2 = (const float*)d_in[9];
    const float* g2 = (const float*)d_in[10];
    const float* be2 = (const float*)d_in[11];
    const float* rm2 = (const float*)d_in[12];
    const float* rv2 = (const float*)d_in[13];
    const float* W3 = (const float*)d_in[14];
    const float* b3 = (const float*)d_in[15];
    float* out = (float*)d_out;

    char* p = (char*)d_ws;
    auto carve = [&](size_t bytes) -> void* {
        void* r = (void*)p;
        p += (bytes + 255) & ~(size_t)255;
        return r;
    };
    int* rp     = (int*)carve((size_t)(NN + 1) * 4);
    float* dinv = (float*)carve((size_t)NN * 4);
    int* col    = (int*)carve((size_t)(EE + NN) * 4);
    int* bbase  = (int*)carve(256 * 4);
    float* sc1  = (float*)carve(128 * 4);
    float* sh1  = (float*)carve(128 * 4);
    float* sc2  = (float*)carve(128 * 4);
    float* sh2  = (float*)carve(128 * 4);
    _Float16* bufA = (_Float16*)carve((size_t)NN * CH * 2);
    _Float16* bufB = (_Float16*)carve((size_t)NN * CH * 2);
    _Float16* Wt1  = (_Float16*)carve(128 * 128 * 2);
    _Float16* Wt2  = (_Float16*)carve(128 * 128 * 2);
    float* h3   = (float*)carve((size_t)NN * 2 * 4);

    // bucket workspace aliases bufA (dead until first GEMM)
    int* eb   = (int*)bufA;
    int* gcur = eb + (size_t)NBUCK * CAP_E;

    hipMemsetAsync(gcur, 0, (size_t)NBUCK * 4, stream);

    k_passA<<<(EE + 4095) / 4096, 256, 0, stream>>>(src, dst, gcur, eb);
    k_bscan<<<1, 256, 0, stream>>>(gcur, bbase, rp);
    k_passB<<<NBUCK, 256, 0, stream>>>(gcur, eb, bbase, rp, dinv, col);
    k_prep<<<258, 128, 0, stream>>>(W1, W2, Wt1, Wt2,
                                    b1, g1, be1, rm1, rv1,
                                    b2, g2, be2, rm2, rv2,
                                    sc1, sh1, sc2, sh2);

    int aggBlocks = 8 * (NN / 32);   // NN % 32 == 0
    k_gemm_mfma<true><<<(NN + 63) / 64, 256, 0, stream>>>(x, Wt1, dinv, bufA);
    k_aggs3<<<aggBlocks, 256, 0, stream>>>(bufA, rp, col, dinv, sc1, sh1, bufB);
    k_gemm_mfma<false><<<(NN + 63) / 64, 256, 0, stream>>>(bufB, Wt2, dinv, bufA);
    k_aggs3<<<aggBlocks, 256, 0, stream>>>(bufA, rp, col, dinv, sc2, sh2, bufB);
    k_gemm_out<<<(NN + 255) / 256, 256, 0, stream>>>(bufB, W3, dinv, h3);
    k_agg_out<<<(NN + 255) / 256, 256, 0, stream>>>(h3, rp, col, dinv, b3, out);
}